// Round 1
// baseline (232.446 us; speedup 1.0000x reference)
//
#include <hip/hip_runtime.h>

#define HWZ 32768   // 64*64*8 spatial positions
#define NH 8
#define HD 16

// workspace layout (float offsets)
#define MU_OFF   0
#define RS_OFF   128
#define BEFF_OFF 256
#define WEFF_OFF 1024                      // 128*384 = 49152 floats
#define Q_OFF    65536
#define K_OFF    (Q_OFF + NH*HWZ*HD)       // +4194304
#define V_OFF    (K_OFF + NH*HWZ*HD)
#define AO_OFF   (V_OFF + NH*HWZ*HD)       // 32768*128 floats

// ---------------- per-channel mean / rsqrt(var) ----------------
__global__ void stats_kernel(const float* __restrict__ x, float* __restrict__ ws) {
    int ch = blockIdx.x;
    const float4* xp = (const float4*)(x + (size_t)ch * HWZ);
    float s = 0.f, ss = 0.f;
    for (int i = threadIdx.x; i < HWZ / 4; i += blockDim.x) {
        float4 v = xp[i];
        s  += v.x + v.y + v.z + v.w;
        ss += v.x*v.x + v.y*v.y + v.z*v.z + v.w*v.w;
    }
    for (int off = 32; off; off >>= 1) {
        s  += __shfl_down(s, off);
        ss += __shfl_down(ss, off);
    }
    __shared__ float as_[4], bs_[4];
    int lane = threadIdx.x & 63, wid = threadIdx.x >> 6;
    if (lane == 0) { as_[wid] = s; bs_[wid] = ss; }
    __syncthreads();
    if (threadIdx.x == 0) {
        float S = 0.f, SS = 0.f;
        for (int w = 0; w < 4; w++) { S += as_[w]; SS += bs_[w]; }
        float mu  = S / (float)HWZ;
        float var = SS / (float)HWZ - mu * mu;
        ws[MU_OFF + ch] = mu;
        ws[RS_OFF + ch] = rsqrtf(var + 1e-5f);
    }
}

// ---------------- fold LN into qkv weights ----------------
__global__ void weff_kernel(const float* __restrict__ w_qkv,
                            const float* __restrict__ b_qkv,
                            float* __restrict__ ws) {
    int j = threadIdx.x;   // 0..383
    float acc = 0.f;
    for (int c = 0; c < 128; c++) {
        float w  = w_qkv[c * 384 + j];
        float we = ws[RS_OFF + c] * w;
        ws[WEFF_OFF + c * 384 + j] = we;
        acc += ws[MU_OFF + c] * we;
    }
    ws[BEFF_OFF + j] = b_qkv[j] - acc;
}

// ---------------- QKV GEMM: qkv[p, j] = sum_c x[c, p] * w_eff[c, j] ----------------
// block: 384 threads, tile = 32 positions. Thread owns one j, 32 position accumulators.
__global__ void qkv_kernel(const float* __restrict__ x, float* __restrict__ ws) {
    __shared__ float xs[128 * 32];
    int p0 = blockIdx.x * 32;
    for (int idx = threadIdx.x; idx < 4096; idx += 384) {
        int c = idx >> 5, pl = idx & 31;
        xs[idx] = x[(size_t)c * HWZ + p0 + pl];
    }
    __syncthreads();
    int j = threadIdx.x;
    float acc[32];
#pragma unroll
    for (int p = 0; p < 32; p++) acc[p] = 0.f;
    const float* we = ws + WEFF_OFF + j;
    for (int c = 0; c < 128; c++) {
        float w = we[c * 384];
        const float4* xr = (const float4*)(xs + c * 32);
#pragma unroll
        for (int p4 = 0; p4 < 8; p4++) {
            float4 xv = xr[p4];
            acc[p4*4+0] += xv.x * w;
            acc[p4*4+1] += xv.y * w;
            acc[p4*4+2] += xv.z * w;
            acc[p4*4+3] += xv.w * w;
        }
    }
    float b = ws[BEFF_OFF + j];
    int which = j >> 7;            // 0=q, 1=k, 2=v
    int head  = (j & 127) >> 4;
    int d     = j & 15;
    float* dst = ws + (which == 0 ? Q_OFF : (which == 1 ? K_OFF : V_OFF));
    float scale = (which == 0) ? 0.25f : 1.0f;   // hd^-0.5 = 1/4
    for (int p = 0; p < 32; p++) {
        dst[((size_t)head * HWZ + p0 + p) * 16 + d] = (acc[p] + b) * scale;
    }
}

// ---------------- NATTEN 3x3x3 attention, one thread per (position, head) ----------------
__global__ void attn_kernel(const float* __restrict__ rpb, float* __restrict__ ws) {
    int g = blockIdx.x * 256 + threadIdx.x;
    int p = g & (HWZ - 1);
    int head = g >> 15;
    int zi = p & 7, wi = (p >> 3) & 63, hi = p >> 9;
    int sh = min(max(hi - 1, 0), 61);
    int sw = min(max(wi - 1, 0), 61);
    int sz = min(max(zi - 1, 0), 5);

    const float* qp = ws + Q_OFF + ((size_t)head * HWZ + p) * 16;
    float q[16];
#pragma unroll
    for (int d4 = 0; d4 < 4; d4++) {
        float4 v = ((const float4*)qp)[d4];
        q[d4*4+0] = v.x; q[d4*4+1] = v.y; q[d4*4+2] = v.z; q[d4*4+3] = v.w;
    }
    const float* kbase = ws + K_OFF + (size_t)head * HWZ * 16;
    const float* vbase = ws + V_OFF + (size_t)head * HWZ * 16;
    // bias base: rel = (start - i + 2) + {a,b,c}
    const float* rp = rpb + head * 125 + (sh - hi + 2) * 25 + (sw - wi + 2) * 5 + (sz - zi + 2);

    float l[27];
    float m = -1e30f;
#pragma unroll
    for (int a = 0; a < 3; a++)
#pragma unroll
    for (int b = 0; b < 3; b++)
#pragma unroll
    for (int c = 0; c < 3; c++) {
        int np_ = (sh + a) * 512 + (sw + b) * 8 + (sz + c);
        const float4* kp = (const float4*)(kbase + (size_t)np_ * 16);
        float dot = 0.f;
#pragma unroll
        for (int d4 = 0; d4 < 4; d4++) {
            float4 kv = kp[d4];
            dot += q[d4*4+0]*kv.x + q[d4*4+1]*kv.y + q[d4*4+2]*kv.z + q[d4*4+3]*kv.w;
        }
        float lg = dot + rp[a * 25 + b * 5 + c];
        l[a*9 + b*3 + c] = lg;
        m = fmaxf(m, lg);
    }
    float s = 0.f;
#pragma unroll
    for (int n = 0; n < 27; n++) { l[n] = expf(l[n] - m); s += l[n]; }
    float inv = 1.f / s;

    float o[16];
#pragma unroll
    for (int d = 0; d < 16; d++) o[d] = 0.f;
#pragma unroll
    for (int a = 0; a < 3; a++)
#pragma unroll
    for (int b = 0; b < 3; b++)
#pragma unroll
    for (int c = 0; c < 3; c++) {
        int np_ = (sh + a) * 512 + (sw + b) * 8 + (sz + c);
        const float4* vp = (const float4*)(vbase + (size_t)np_ * 16);
        float w = l[a*9 + b*3 + c];
#pragma unroll
        for (int d4 = 0; d4 < 4; d4++) {
            float4 vv = vp[d4];
            o[d4*4+0] += w * vv.x; o[d4*4+1] += w * vv.y;
            o[d4*4+2] += w * vv.z; o[d4*4+3] += w * vv.w;
        }
    }
    float* aop = ws + AO_OFF + (size_t)p * 128 + head * 16;
#pragma unroll
    for (int d4 = 0; d4 < 4; d4++) {
        float4 vv;
        vv.x = o[d4*4+0] * inv; vv.y = o[d4*4+1] * inv;
        vv.z = o[d4*4+2] * inv; vv.w = o[d4*4+3] * inv;
        ((float4*)aop)[d4] = vv;
    }
}

// ---------------- output projection: out[c, p] = sum_c' ao[p, c'] * w_proj[c', c] + b_proj[c] ----------------
__global__ void proj_kernel(const float* __restrict__ w_proj,
                            const float* __restrict__ b_proj,
                            const float* __restrict__ ws_c,
                            float* __restrict__ out) {
    __shared__ float as_[32][129];   // +1 pad: conflict-free as_[pl][c'] reads
    int p0 = blockIdx.x * 32;
    const float* ao = ws_c + AO_OFF;
    for (int idx = threadIdx.x; idx < 4096; idx += 256) {
        int pl = idx >> 7, c = idx & 127;
        as_[pl][c] = ao[(size_t)(p0 + pl) * 128 + c];
    }
    __syncthreads();
    int pl = threadIdx.x & 31;
    int cb = (threadIdx.x >> 5) * 16;   // 8 channel groups of 16
    float acc[16];
#pragma unroll
    for (int i = 0; i < 16; i++) acc[i] = b_proj[cb + i];
    for (int cp = 0; cp < 128; cp++) {
        float a = as_[pl][cp];
        const float4* wp = (const float4*)(w_proj + cp * 128 + cb);
#pragma unroll
        for (int i4 = 0; i4 < 4; i4++) {
            float4 w = wp[i4];
            acc[i4*4+0] += a * w.x; acc[i4*4+1] += a * w.y;
            acc[i4*4+2] += a * w.z; acc[i4*4+3] += a * w.w;
        }
    }
#pragma unroll
    for (int i = 0; i < 16; i++) {
        out[(size_t)(cb + i) * HWZ + p0 + pl] = acc[i];
    }
}

extern "C" void kernel_launch(void* const* d_in, const int* in_sizes, int n_in,
                              void* d_out, int out_size, void* d_ws, size_t ws_size,
                              hipStream_t stream) {
    const float* x      = (const float*)d_in[0];
    const float* w_qkv  = (const float*)d_in[1];
    const float* b_qkv  = (const float*)d_in[2];
    const float* rpb    = (const float*)d_in[3];
    const float* w_proj = (const float*)d_in[4];
    const float* b_proj = (const float*)d_in[5];
    float* out = (float*)d_out;
    float* ws  = (float*)d_ws;

    stats_kernel<<<128, 256, 0, stream>>>(x, ws);
    weff_kernel<<<1, 384, 0, stream>>>(w_qkv, b_qkv, ws);
    qkv_kernel<<<1024, 384, 0, stream>>>(x, ws);
    attn_kernel<<<1024, 256, 0, stream>>>(rpb, ws);
    proj_kernel<<<1024, 256, 0, stream>>>(w_proj, b_proj, ws, out);
}